// Round 2
// baseline (677.030 us; speedup 1.0000x reference)
//
#include <hip/hip_runtime.h>
#include <math.h>

#define DEV __device__ __forceinline__

// ---------------- combo metadata ----------------
// combos (l, l1, l2) in reference order; sizes D*D1*D2; prefix offsets
__constant__ int C_L [11] = {0,0,0, 2,2,2,2, 4,4,4,4};
__constant__ int C_L1[11] = {0,2,4, 0,2,2,4, 0,2,2,4};
__constant__ int C_L2[11] = {0,2,4, 2,2,4,4, 4,2,4,4};
__constant__ int C_OFF[11]= {0,1,26,107,132,257,482,887,968,1193,1598};
// total CG floats per table = 2327; CGR at ws[0..2327), CGL at ws[2327..4654)

__constant__ double FACT[14] = {1.,1.,2.,6.,24.,120.,720.,5040.,40320.,362880.,
                                3628800.,39916800.,479001600.,6227020800.};

DEV int imax(int a, int b) { return a > b ? a : b; }
DEV int imin(int a, int b) { return a < b ? a : b; }

DEV double su2cg(int j1, int m1, int j2, int m2, int j3, int m3) {
  if (m3 != m1 + m2) return 0.0;
  int vmin = imax(imax(-j1 + j2 + m3, -j1 + m1), 0);
  int vmax = imin(imin(j2 + j3 + m1, j3 - j1 + j2), j3 + m3);
  if (vmax < vmin) return 0.0;
  double C = sqrt((2.0 * j3 + 1.0)
      * FACT[j3 + j1 - j2] * FACT[j3 - j1 + j2] * FACT[j1 + j2 - j3]
      * FACT[j3 + m3] * FACT[j3 - m3]
      / (FACT[j1 + j2 + j3 + 1] * FACT[j1 - m1] * FACT[j1 + m1]
         * FACT[j2 - m2] * FACT[j2 + m2]));
  double S = 0.0;
  for (int v = vmin; v <= vmax; ++v) {
    double term = FACT[j2 + j3 + m1 - v] * FACT[j1 - m1 + v]
        / (FACT[v] * FACT[j3 - j1 + j2 - v] * FACT[j3 + m3 - v]
           * FACT[v + j1 - j2 - m3]);
    S += ((v + j2 + m2) & 1) ? -term : term;
  }
  return C * S;
}

struct Cpx { double x, y; };

// nonzero entries of column c of e3nn's real->complex Q matrix for even l
// (factor (-i)^l is real: +1 for l%4==0, -1 for l%4==2)
DEV int qcol(int l, int c, int* rows, Cpx* vals) {
  const double r2 = 0.70710678118654752440;
  double sg = (l % 4 == 2) ? -1.0 : 1.0;
  if (c == l) { rows[0] = l; vals[0] = {sg, 0.0}; return 1; }
  if (c > l) {
    int mm = c - l;
    double par = (mm & 1) ? -1.0 : 1.0;
    rows[0] = l - mm; vals[0] = {sg * r2, 0.0};
    rows[1] = l + mm; vals[1] = {sg * par * r2, 0.0};
    return 2;
  }
  int mm = l - c;
  double par = (mm & 1) ? -1.0 : 1.0;
  rows[0] = l - mm; vals[0] = {0.0, -sg * r2};
  rows[1] = l + mm; vals[1] = {0.0, sg * par * r2};
  return 2;
}

// blocks 0..10: compute cg_r/cg_l tables for combo blockIdx.x into ws
// block 11: copy raw feats into the feats_out region of d_out
// Restructured R1: complex CG computed ONCE per (m1,m2) pair in parallel
// (81 threads, one su2cg each) instead of up to 8 serial su2cg per entry.
__global__ void cg_setup_kernel(float* __restrict__ ws,
                                const float* __restrict__ feats,
                                float* __restrict__ out) {
  int c = blockIdx.x;
  int tid = threadIdx.x;
  if (c == 11) {
    for (int i = tid; i < 1024; i += 256) {
      int n = i >> 6, j = i & 63;
      out[7012352 + n * 12352 + j] = feats[i];
    }
    return;
  }
  __shared__ double ccg[81];
  __shared__ double wbuf[729];
  __shared__ double red[256];
  const int l = C_L[c], l1 = C_L1[c], l2 = C_L2[c];
  const int D = 2 * l + 1, D1 = 2 * l1 + 1, D2 = 2 * l2 + 1;
  const int n = D * D1 * D2;
  const int off = C_OFF[c];

  // phase 1: complex CG table, one su2cg per thread (parallel)
  if (tid < D1 * D2) {
    int a = tid / D2, b = tid % D2;
    int m1 = a - l1, m2 = b - l2, m3 = m1 + m2;
    ccg[tid] = (m3 >= -l && m3 <= l) ? su2cg(l1, m1, l2, m2, l, m3) : 0.0;
  }
  __syncthreads();

  // phase 2: real-basis transform
  // w[a][b][k] = Re( sum Q1[r1,a] Q2[r2,b] conj(Q3[r3,k]) C[r1,r2,r3] )
  for (int e = tid; e < n; e += 256) {
    int k = e % D; int ab = e / D; int b = ab % D2; int a = ab / D2;
    int r1[2], r2a[2], r3[2];
    Cpx v1[2], v2[2], v3[2];
    int n1 = qcol(l1, a, r1, v1);
    int n2 = qcol(l2, b, r2a, v2);
    int n3 = qcol(l, k, r3, v3);
    double s = 0.0;
    for (int i1 = 0; i1 < n1; ++i1) {
      for (int i2 = 0; i2 < n2; ++i2) {
        int m1 = r1[i1] - l1, m2 = r2a[i2] - l2;
        Cpx p12 = {v1[i1].x * v2[i2].x - v1[i1].y * v2[i2].y,
                   v1[i1].x * v2[i2].y + v1[i1].y * v2[i2].x};
        for (int i3 = 0; i3 < n3; ++i3) {
          int m3 = r3[i3] - l;
          if (m3 != m1 + m2) continue;
          double cg = ccg[r1[i1] * D2 + r2a[i2]];
          // Re(p12 * conj(v3))
          s += (p12.x * v3[i3].x + p12.y * v3[i3].y) * cg;
        }
      }
    }
    wbuf[e] = s;
  }
  __syncthreads();
  double part = 0.0;
  for (int e = tid; e < n; e += 256) part += wbuf[e] * wbuf[e];
  red[tid] = part;
  __syncthreads();
  for (int st = 128; st > 0; st >>= 1) {
    if (tid < st) red[tid] += red[tid + st];
    __syncthreads();
  }
  double scale = (l1 != l2) ? 1.41421356237309504880 : 1.0;
  double inv = scale / sqrt(red[0]);
  // cg (D,D2,D1) = transpose(w,(2,1,0)); cg_r = raw reshape to (D,D1,D2);
  // cg_l = transpose(cg_r,(0,2,1))
  for (int o = tid; o < n; o += 256) {
    int k = o / (D1 * D2); int t = o % (D1 * D2);
    int a = t % D1; int b = t / D1;     // w[a][b][k]
    int x = t / D2; int y = t % D2;     // cg_r[k][x][y]
    float val = (float)(wbuf[(a * D2 + b) * D + k] * inv);
    ws[off + o] = val;                                  // CGR: k*D1*D2 + x*D2 + y
    ws[2327 + off + k * (D1 * D2) + y * D1 + x] = val;  // CGL: k*D1*D2 + y*D1 + x
  }
}

// ---------------- main compute ----------------
// LDS layout: lds[(elem)*65 + site], elem: 0 = rh0, 1..25 = rh2, 26..106 = rh4

template<int D, int D1, int D2>
DEV void run_combo(const float* __restrict__ cgr, const float* __restrict__ cgl,
                   const float* __restrict__ A, const float* __restrict__ B,
                   int lane, float* __restrict__ acc, int q0, int q1) {
  #pragma unroll 1
  for (int q = q0; q < q1; ++q) {
    float Brow[D2];
    #pragma unroll
    for (int j = 0; j < D2; ++j) Brow[j] = B[(q * D2 + j) * 65 + lane];
    const float* cglq = cgl + q * D1;
    // unroll 2: two p-iterations in flight -> s_load(cg)/ds_read latency overlap
    #pragma unroll 2
    for (int p = 0; p < D1; ++p) {
      float Acol[D1];
      #pragma unroll
      for (int j = 0; j < D1; ++j) Acol[j] = A[(j * D1 + p) * 65 + lane];
      const float* cgrp = cgr + p * D2;
      float vl[D], vr[D];
      #pragma unroll
      for (int k = 0; k < D; ++k) {
        float s = 0.f;
        #pragma unroll
        for (int j = 0; j < D1; ++j) s = fmaf(Acol[j], cglq[k * D1 * D2 + j], s);
        vl[k] = s;
      }
      #pragma unroll
      for (int k = 0; k < D; ++k) {
        float s = 0.f;
        #pragma unroll
        for (int j = 0; j < D2; ++j) s = fmaf(Brow[j], cgrp[k * D1 * D2 + j], s);
        vr[k] = s;
      }
      #pragma unroll
      for (int k1 = 0; k1 < D; ++k1) {
        #pragma unroll
        for (int k2 = 0; k2 < D; ++k2)
          acc[k1 * D + k2] = fmaf(vl[k1], vr[k2], acc[k1 * D + k2]);
      }
    }
  }
}

__global__ __launch_bounds__(256, 4)
void quad_main(const float* __restrict__ rh0, const float* __restrict__ rh2,
               const float* __restrict__ rh4, const float* __restrict__ ws,
               float* __restrict__ out) {
  __shared__ float lds[107 * 65];
  const int tid = threadIdx.x;
  const int lane = tid & 63;
  const int wave = tid >> 6;
  const int blk = blockIdx.x;
  const int site0 = blk * 64;

  // stage 64 sites into LDS (coalesced global reads, conflict-free LDS writes)
  if (tid < 64) lds[tid] = rh0[site0 + tid];
  for (int f = tid; f < 1600; f += 256) {
    int s = f / 25, e = f - s * 25;
    lds[(1 + e) * 65 + s] = rh2[site0 * 25 + f];
  }
  for (int f = tid; f < 5184; f += 256) {
    int s = f / 81, e = f - s * 81;
    lds[(26 + e) * 65 + s] = rh4[site0 * 81 + f];
  }
  __syncthreads();

  const float* r0 = lds;
  const float* r2l = lds + 65;
  const float* r4l = lds + 26 * 65;
  const float* CGR = ws;
  const float* CGL = ws + 2327;

  float acc0[1] = {0.f};
  float acc2[25], acc4[81];
  #pragma unroll
  for (int i = 0; i < 25; ++i) acc2[i] = 0.f;
  #pragma unroll
  for (int i = 0; i < 81; ++i) acc4[i] = 0.f;

  // combo work split across 4 waves, balanced (FMA/wave: 13122/13590/13590/12067)
  if (wave == 0) {
    run_combo<9,9,9>(CGR + 1598, CGL + 1598, r4l, r4l, lane, acc4, 0, 6);  // c10 q0..5
  } else if (wave == 1) {
    run_combo<5,9,9>(CGR + 482, CGL + 482, r4l, r4l, lane, acc2, 0, 9);    // (2,4,4)
    run_combo<5,5,9>(CGR + 257, CGL + 257, r2l, r4l, lane, acc2, 0, 9);    // (2,2,4)
  } else if (wave == 2) {
    run_combo<9,5,9>(CGR + 1193, CGL + 1193, r2l, r4l, lane, acc4, 0, 9);  // (4,2,4)
    run_combo<9,5,5>(CGR + 968, CGL + 968, r2l, r2l, lane, acc4, 0, 5);    // (4,2,2)
  } else {
    run_combo<9,9,9>(CGR + 1598, CGL + 1598, r4l, r4l, lane, acc4, 6, 9);  // c10 q6..8
    run_combo<1,9,9>(CGR + 26, CGL + 26, r4l, r4l, lane, acc0, 0, 9);      // (0,4,4)
    run_combo<9,1,9>(CGR + 887, CGL + 887, r0, r4l, lane, acc4, 0, 9);     // (4,0,4)
    run_combo<5,5,5>(CGR + 132, CGL + 132, r2l, r2l, lane, acc2, 0, 5);    // (2,2,2)
    run_combo<5,1,5>(CGR + 107, CGL + 107, r0, r2l, lane, acc2, 0, 5);     // (2,0,2)
    run_combo<1,5,5>(CGR + 1, CGL + 1, r2l, r2l, lane, acc0, 0, 5);        // (0,2,2)
    run_combo<1,1,1>(CGR + 0, CGL + 0, r0, r0, lane, acc0, 0, 1);          // (0,0,0)
  }

  // merge: zero the (now-dead) staging region, then all waves ds_add_f32 in parallel
  __syncthreads();
  for (int i = tid; i < 107 * 65; i += 256) lds[i] = 0.f;
  __syncthreads();
  if (wave == 0) {
    #pragma unroll
    for (int e = 0; e < 81; ++e) atomicAdd(&lds[(26 + e) * 65 + lane], acc4[e]);
  } else if (wave == 1) {
    #pragma unroll
    for (int e = 0; e < 25; ++e) atomicAdd(&lds[(1 + e) * 65 + lane], acc2[e]);
  } else if (wave == 2) {
    #pragma unroll
    for (int e = 0; e < 81; ++e) atomicAdd(&lds[(26 + e) * 65 + lane], acc4[e]);
  } else {
    atomicAdd(&lds[lane], acc0[0]);
    #pragma unroll
    for (int e = 0; e < 25; ++e) atomicAdd(&lds[(1 + e) * 65 + lane], acc2[e]);
    #pragma unroll
    for (int e = 0; e < 81; ++e) atomicAdd(&lds[(26 + e) * 65 + lane], acc4[e]);
  }
  __syncthreads();

  // coalesced stores: rh_n[0] | rh_n[2] | rh_n[4]
  if (tid < 64) out[site0 + tid] = lds[tid];
  for (int f = tid; f < 1600; f += 256) {
    int s = f / 25, e = f - s * 25;
    out[65536 + blk * 1600 + f] = lds[(1 + e) * 65 + s];
  }
  for (int f = tid; f < 5184; f += 256) {
    int s = f / 81, e = f - s * 81;
    out[1703936 + blk * 5184 + f] = lds[(26 + e) * 65 + s];
  }

  // rotation-invariant features
  if (tid < 64) {
    int site = site0 + tid;
    int nn = site >> 12, abc = site & 4095;
    float v0 = lds[tid];
    float f0 = v0 * v0;
    float s2 = 0.f;
    #pragma unroll
    for (int e = 0; e < 25; ++e) { float v = lds[(1 + e) * 65 + tid]; s2 = fmaf(v, v, s2); }
    float s4 = 0.f;
    #pragma unroll
    for (int e = 0; e < 81; ++e) { float v = lds[(26 + e) * 65 + tid]; s4 = fmaf(v, v, s4); }
    const float PI8 = 78.95683520871486f;  // 8*pi^2
    int base = 7012352 + nn * 12352 + 64;
    out[base + abc] = PI8 * f0;
    out[base + 4096 + abc] = (PI8 / 5.f) * s2;
    out[base + 8192 + abc] = (PI8 / 9.f) * s4;
  }
}

extern "C" void kernel_launch(void* const* d_in, const int* in_sizes, int n_in,
                              void* d_out, int out_size, void* d_ws, size_t ws_size,
                              hipStream_t stream) {
  const float* rh0 = (const float*)d_in[0];
  const float* rh2 = (const float*)d_in[1];
  const float* rh4 = (const float*)d_in[2];
  const float* feats = (const float*)d_in[3];
  float* out = (float*)d_out;
  float* ws = (float*)d_ws;
  // CG tables -> d_ws (recomputed every call; ws is re-poisoned by harness)
  cg_setup_kernel<<<12, 256, 0, stream>>>(ws, feats, out);
  // main quadratic nonlinearity
  quad_main<<<1024, 256, 0, stream>>>(rh0, rh2, rh4, ws, out);
}

// Round 3
// 281.908 us; speedup vs baseline: 2.4016x; 2.4016x over previous
//
#include <hip/hip_runtime.h>
#include <math.h>

#define DEV __device__ __forceinline__

// ================= compile-time CG tables =================
// Reproduces the reference's real-basis Wigner-3j derived cg_r/cg_l tables
// entirely at compile time -> __constant__ memory. No setup kernel.

constexpr double FC[14] = {1.,1.,2.,6.,24.,120.,720.,5040.,40320.,362880.,
                           3628800.,39916800.,479001600.,6227020800.};

constexpr double csqrt(double x) {
  if (x <= 0.0) return 0.0;
  double g = x > 1.0 ? x : 1.0;
  double p = 0.0;
  for (int i = 0; i < 64 && g != p; ++i) { p = g; g = 0.5 * (g + x / g); }
  return g;
}

constexpr int cimax(int a, int b) { return a > b ? a : b; }
constexpr int cimin(int a, int b) { return a < b ? a : b; }

constexpr double su2cg_c(int j1, int m1, int j2, int m2, int j3, int m3) {
  if (m3 != m1 + m2) return 0.0;
  int vmin = cimax(cimax(-j1 + j2 + m3, -j1 + m1), 0);
  int vmax = cimin(cimin(j2 + j3 + m1, j3 - j1 + j2), j3 + m3);
  if (vmax < vmin) return 0.0;
  double C = csqrt((2.0 * j3 + 1.0)
      * FC[j3 + j1 - j2] * FC[j3 - j1 + j2] * FC[j1 + j2 - j3]
      * FC[j3 + m3] * FC[j3 - m3]
      / (FC[j1 + j2 + j3 + 1] * FC[j1 - m1] * FC[j1 + m1]
         * FC[j2 - m2] * FC[j2 + m2]));
  double S = 0.0;
  for (int v = vmin; v <= vmax; ++v) {
    double term = FC[j2 + j3 + m1 - v] * FC[j1 - m1 + v]
        / (FC[v] * FC[j3 - j1 + j2 - v] * FC[j3 + m3 - v]
           * FC[v + j1 - j2 - m3]);
    S += ((v + j2 + m2) & 1) ? -term : term;
  }
  return C * S;
}

// nonzeros of column c of real->complex Q for even l ((-i)^l real: +/-1)
constexpr int nqcol(int l, int c, int* rows, double* vx, double* vy) {
  const double r2 = 0.70710678118654752440;
  double sg = (l % 4 == 2) ? -1.0 : 1.0;
  if (c == l) { rows[0] = l; vx[0] = sg; vy[0] = 0.0; return 1; }
  if (c > l) {
    int mm = c - l;
    double par = (mm & 1) ? -1.0 : 1.0;
    rows[0] = l - mm; vx[0] = sg * r2;       vy[0] = 0.0;
    rows[1] = l + mm; vx[1] = sg * par * r2; vy[1] = 0.0;
    return 2;
  }
  int mm = l - c;
  double par = (mm & 1) ? -1.0 : 1.0;
  rows[0] = l - mm; vx[0] = 0.0; vy[0] = -sg * r2;
  rows[1] = l + mm; vx[1] = 0.0; vy[1] = sg * par * r2;
  return 2;
}

constexpr int KCL [11] = {0,0,0, 2,2,2,2, 4,4,4,4};
constexpr int KCL1[11] = {0,2,4, 0,2,2,4, 0,2,2,4};
constexpr int KCL2[11] = {0,2,4, 2,2,4,4, 4,2,4,4};
constexpr int KOFF[11] = {0,1,26,107,132,257,482,887,968,1193,1598};

// stage 1 (own constexpr step budget): complex CG per combo
struct CCGT { double v[11][81]; };
constexpr CCGT make_ccg() {
  CCGT z = {};
  for (int c = 0; c < 11; ++c) {
    int l = KCL[c], l1 = KCL1[c], l2 = KCL2[c];
    int D1 = 2 * l1 + 1, D2 = 2 * l2 + 1;
    for (int a = 0; a < D1; ++a)
      for (int b = 0; b < D2; ++b) {
        int m1 = a - l1, m2 = b - l2, m3 = m1 + m2;
        z.v[c][a * D2 + b] =
            (m3 >= -l && m3 <= l) ? su2cg_c(l1, m1, l2, m2, l, m3) : 0.0;
      }
  }
  return z;
}
constexpr CCGT CCG = make_ccg();

// stage 2: real-basis transform + norm + sqrt2 scale -> cg_r / cg_l
struct CGTab { float r[2327]; float l[2327]; };
constexpr CGTab make_tables(const CCGT& cc) {
  CGTab t = {};
  for (int c = 0; c < 11; ++c) {
    int l = KCL[c], l1 = KCL1[c], l2 = KCL2[c];
    int D = 2 * l + 1, D1 = 2 * l1 + 1, D2 = 2 * l2 + 1;
    int n = D * D1 * D2, off = KOFF[c];
    double wbuf[729] = {};
    for (int e = 0; e < n; ++e) {
      int k = e % D; int ab = e / D; int b = ab % D2; int a = ab / D2;
      int r1[2] = {}, r2[2] = {}, r3[2] = {};
      double x1[2] = {}, y1[2] = {}, x2[2] = {}, y2[2] = {}, x3[2] = {}, y3[2] = {};
      int n1 = nqcol(l1, a, r1, x1, y1);
      int n2 = nqcol(l2, b, r2, x2, y2);
      int n3 = nqcol(l, k, r3, x3, y3);
      double s = 0.0;
      for (int i1 = 0; i1 < n1; ++i1)
        for (int i2 = 0; i2 < n2; ++i2) {
          double px = x1[i1] * x2[i2] - y1[i1] * y2[i2];
          double py = x1[i1] * y2[i2] + y1[i1] * x2[i2];
          int m12 = (r1[i1] - l1) + (r2[i2] - l2);
          for (int i3 = 0; i3 < n3; ++i3) {
            if (r3[i3] - l != m12) continue;
            s += (px * x3[i3] + py * y3[i3]) * cc.v[c][r1[i1] * D2 + r2[i2]];
          }
        }
      wbuf[e] = s;
    }
    double ss = 0.0;
    for (int e = 0; e < n; ++e) ss += wbuf[e] * wbuf[e];
    double inv = (l1 != l2 ? 1.41421356237309504880 : 1.0) / csqrt(ss);
    for (int o = 0; o < n; ++o) {
      int k = o / (D1 * D2), tt = o % (D1 * D2);
      int a = tt % D1, b = tt / D1;   // w[a][b][k]
      int x = tt / D2, y = tt % D2;   // cg_r[k][x][y]
      double val = wbuf[(a * D2 + b) * D + k] * inv;
      t.r[off + o] = (float)val;                          // k*D1*D2 + x*D2 + y
      t.l[off + k * (D1 * D2) + y * D1 + x] = (float)val; // k*D1*D2 + y*D1 + x
    }
  }
  return t;
}
__constant__ CGTab G = make_tables(CCG);

// ================= main compute =================
// LDS layout: lds[elem*65 + site], elem: 0 = rh0, 1..25 = rh2, 26..106 = rh4

template<int D, int D1, int D2>
DEV void run_combo(const float* __restrict__ cgr, const float* __restrict__ cgl,
                   const float* __restrict__ A, const float* __restrict__ B,
                   int lane, float* __restrict__ acc, int q0, int q1) {
  #pragma unroll 1
  for (int q = q0; q < q1; ++q) {
    float Brow[D2];
    #pragma unroll
    for (int j = 0; j < D2; ++j) Brow[j] = B[(q * D2 + j) * 65 + lane];
    const float* cglq = cgl + q * D1;
    #pragma unroll 1
    for (int p = 0; p < D1; ++p) {
      float Acol[D1];
      #pragma unroll
      for (int j = 0; j < D1; ++j) Acol[j] = A[(j * D1 + p) * 65 + lane];
      const float* cgrp = cgr + p * D2;
      float vl[D], vr[D];
      #pragma unroll
      for (int k = 0; k < D; ++k) {
        float s = 0.f;
        #pragma unroll
        for (int j = 0; j < D1; ++j) s = fmaf(Acol[j], cglq[k * D1 * D2 + j], s);
        vl[k] = s;
      }
      #pragma unroll
      for (int k = 0; k < D; ++k) {
        float s = 0.f;
        #pragma unroll
        for (int j = 0; j < D2; ++j) s = fmaf(Brow[j], cgrp[k * D1 * D2 + j], s);
        vr[k] = s;
      }
      #pragma unroll
      for (int k1 = 0; k1 < D; ++k1) {
        #pragma unroll
        for (int k2 = 0; k2 < D; ++k2)
          acc[k1 * D + k2] = fmaf(vl[k1], vr[k2], acc[k1 * D + k2]);
      }
    }
  }
}

// block = 256 thr (4 waves), 64 sites. launch_bounds(256,3): 12 waves/CU,
// reg budget ~170/thread (worst path ~155 live: acc 107 + working 36 + addr).
// (256,4)=128 budget spilled catastrophically in R2 -- do not lower.
__global__ __launch_bounds__(256, 3)
void quad_main(const float* __restrict__ rh0, const float* __restrict__ rh2,
               const float* __restrict__ rh4, const float* __restrict__ feats,
               float* __restrict__ out) {
  __shared__ float lds[107 * 65];
  const int tid = threadIdx.x;
  const int lane = tid & 63;
  const int wave = tid >> 6;
  const int blk = blockIdx.x;
  const int site0 = blk * 64;

  // feats passthrough (block 0 only; independent of the rest)
  if (blk == 0) {
    for (int i = tid; i < 1024; i += 256) {
      int n = i >> 6, j = i & 63;
      out[7012352 + n * 12352 + j] = feats[i];
    }
  }

  // stage 64 sites into LDS (coalesced global reads, conflict-free LDS writes)
  if (tid < 64) lds[tid] = rh0[site0 + tid];
  for (int f = tid; f < 1600; f += 256) {
    int s = f / 25, e = f - s * 25;
    lds[(1 + e) * 65 + s] = rh2[site0 * 25 + f];
  }
  for (int f = tid; f < 5184; f += 256) {
    int s = f / 81, e = f - s * 81;
    lds[(26 + e) * 65 + s] = rh4[site0 * 81 + f];
  }
  __syncthreads();

  const float* r0 = lds;
  const float* r2l = lds + 65;
  const float* r4l = lds + 26 * 65;
  const float* CGR = G.r;
  const float* CGL = G.l;

  float acc0[1] = {0.f};
  float acc2[25], acc4[81];
  #pragma unroll
  for (int i = 0; i < 25; ++i) acc2[i] = 0.f;
  #pragma unroll
  for (int i = 0; i < 81; ++i) acc4[i] = 0.f;

  // wave split, FMA/wave: 13122 / 13689 / 13291 / 13015 (99% balanced)
  if (wave == 0) {
    run_combo<9,9,9>(CGR + 1598, CGL + 1598, r4l, r4l, lane, acc4, 0, 6);  // (4,4,4) q0-5
  } else if (wave == 1) {
    run_combo<9,5,9>(CGR + 1193, CGL + 1193, r2l, r4l, lane, acc4, 0, 9);  // (4,2,4)
    run_combo<9,9,9>(CGR + 1598, CGL + 1598, r4l, r4l, lane, acc4, 6, 8);  // (4,4,4) q6-7
  } else if (wave == 2) {
    run_combo<9,5,5>(CGR + 968, CGL + 968, r2l, r2l, lane, acc4, 0, 5);    // (4,2,2)
    run_combo<9,1,9>(CGR + 887, CGL + 887, r0, r4l, lane, acc4, 0, 9);     // (4,0,4)
    run_combo<9,9,9>(CGR + 1598, CGL + 1598, r4l, r4l, lane, acc4, 8, 9);  // (4,4,4) q8
    run_combo<1,9,9>(CGR + 26, CGL + 26, r4l, r4l, lane, acc0, 0, 9);      // (0,4,4)
    run_combo<1,1,1>(CGR + 0, CGL + 0, r0, r0, lane, acc0, 0, 1);          // (0,0,0)
    run_combo<5,5,5>(CGR + 132, CGL + 132, r2l, r2l, lane, acc2, 0, 5);    // (2,2,2)
    run_combo<5,1,5>(CGR + 107, CGL + 107, r0, r2l, lane, acc2, 0, 5);     // (2,0,2)
    run_combo<5,5,9>(CGR + 257, CGL + 257, r2l, r4l, lane, acc2, 0, 2);    // (2,2,4) q0-1
  } else {
    run_combo<5,9,9>(CGR + 482, CGL + 482, r4l, r4l, lane, acc2, 0, 9);    // (2,4,4)
    run_combo<5,5,9>(CGR + 257, CGL + 257, r2l, r4l, lane, acc2, 2, 9);    // (2,2,4) q2-8
    run_combo<1,5,5>(CGR + 1, CGL + 1, r2l, r2l, lane, acc0, 0, 5);        // (0,2,2)
  }

  // merge: zero the (now-dead) staging region, then LDS atomics in parallel
  __syncthreads();
  for (int i = tid; i < 107 * 65; i += 256) lds[i] = 0.f;
  __syncthreads();
  if (wave == 0 || wave == 1) {
    #pragma unroll
    for (int e = 0; e < 81; ++e) atomicAdd(&lds[(26 + e) * 65 + lane], acc4[e]);
  } else if (wave == 2) {
    #pragma unroll
    for (int e = 0; e < 81; ++e) atomicAdd(&lds[(26 + e) * 65 + lane], acc4[e]);
    atomicAdd(&lds[lane], acc0[0]);
    #pragma unroll
    for (int e = 0; e < 25; ++e) atomicAdd(&lds[(1 + e) * 65 + lane], acc2[e]);
  } else {
    #pragma unroll
    for (int e = 0; e < 25; ++e) atomicAdd(&lds[(1 + e) * 65 + lane], acc2[e]);
    atomicAdd(&lds[lane], acc0[0]);
  }
  __syncthreads();

  // coalesced stores: rh_n[0] | rh_n[2] | rh_n[4]
  if (tid < 64) out[site0 + tid] = lds[tid];
  for (int f = tid; f < 1600; f += 256) {
    int s = f / 25, e = f - s * 25;
    out[65536 + blk * 1600 + f] = lds[(1 + e) * 65 + s];
  }
  for (int f = tid; f < 5184; f += 256) {
    int s = f / 81, e = f - s * 81;
    out[1703936 + blk * 5184 + f] = lds[(26 + e) * 65 + s];
  }

  // rotation-invariant features
  if (tid < 64) {
    int site = site0 + tid;
    int nn = site >> 12, abc = site & 4095;
    float v0 = lds[tid];
    float f0 = v0 * v0;
    float s2 = 0.f;
    #pragma unroll
    for (int e = 0; e < 25; ++e) { float v = lds[(1 + e) * 65 + tid]; s2 = fmaf(v, v, s2); }
    float s4 = 0.f;
    #pragma unroll
    for (int e = 0; e < 81; ++e) { float v = lds[(26 + e) * 65 + tid]; s4 = fmaf(v, v, s4); }
    const float PI8 = 78.95683520871486f;  // 8*pi^2
    int base = 7012352 + nn * 12352 + 64;
    out[base + abc] = PI8 * f0;
    out[base + 4096 + abc] = (PI8 / 5.f) * s2;
    out[base + 8192 + abc] = (PI8 / 9.f) * s4;
  }
}

extern "C" void kernel_launch(void* const* d_in, const int* in_sizes, int n_in,
                              void* d_out, int out_size, void* d_ws, size_t ws_size,
                              hipStream_t stream) {
  const float* rh0 = (const float*)d_in[0];
  const float* rh2 = (const float*)d_in[1];
  const float* rh4 = (const float*)d_in[2];
  const float* feats = (const float*)d_in[3];
  float* out = (float*)d_out;
  quad_main<<<1024, 256, 0, stream>>>(rh0, rh2, rh4, feats, out);
}

// Round 4
// 205.092 us; speedup vs baseline: 3.3011x; 1.3745x over previous
//
#include <hip/hip_runtime.h>
#include <math.h>

#define DEV __device__ __forceinline__

// ================= compile-time CG tables =================
// All Wigner/CG math runs at compile time; tables land in __constant__ G.
// A tiny kernel copies G -> ws so quad_main reads CG through an OPAQUE
// runtime pointer (forces s_load codegen, prevents const-folding -- R3
// read G directly + bounds(256,3) and regressed 140->230 us).

constexpr double FC[14] = {1.,1.,2.,6.,24.,120.,720.,5040.,40320.,362880.,
                           3628800.,39916800.,479001600.,6227020800.};

constexpr double csqrt(double x) {
  if (x <= 0.0) return 0.0;
  double g = x > 1.0 ? x : 1.0;
  double p = 0.0;
  for (int i = 0; i < 64 && g != p; ++i) { p = g; g = 0.5 * (g + x / g); }
  return g;
}

constexpr int cimax(int a, int b) { return a > b ? a : b; }
constexpr int cimin(int a, int b) { return a < b ? a : b; }

constexpr double su2cg_c(int j1, int m1, int j2, int m2, int j3, int m3) {
  if (m3 != m1 + m2) return 0.0;
  int vmin = cimax(cimax(-j1 + j2 + m3, -j1 + m1), 0);
  int vmax = cimin(cimin(j2 + j3 + m1, j3 - j1 + j2), j3 + m3);
  if (vmax < vmin) return 0.0;
  double C = csqrt((2.0 * j3 + 1.0)
      * FC[j3 + j1 - j2] * FC[j3 - j1 + j2] * FC[j1 + j2 - j3]
      * FC[j3 + m3] * FC[j3 - m3]
      / (FC[j1 + j2 + j3 + 1] * FC[j1 - m1] * FC[j1 + m1]
         * FC[j2 - m2] * FC[j2 + m2]));
  double S = 0.0;
  for (int v = vmin; v <= vmax; ++v) {
    double term = FC[j2 + j3 + m1 - v] * FC[j1 - m1 + v]
        / (FC[v] * FC[j3 - j1 + j2 - v] * FC[j3 + m3 - v]
           * FC[v + j1 - j2 - m3]);
    S += ((v + j2 + m2) & 1) ? -term : term;
  }
  return C * S;
}

constexpr int nqcol(int l, int c, int* rows, double* vx, double* vy) {
  const double r2 = 0.70710678118654752440;
  double sg = (l % 4 == 2) ? -1.0 : 1.0;
  if (c == l) { rows[0] = l; vx[0] = sg; vy[0] = 0.0; return 1; }
  if (c > l) {
    int mm = c - l;
    double par = (mm & 1) ? -1.0 : 1.0;
    rows[0] = l - mm; vx[0] = sg * r2;       vy[0] = 0.0;
    rows[1] = l + mm; vx[1] = sg * par * r2; vy[1] = 0.0;
    return 2;
  }
  int mm = l - c;
  double par = (mm & 1) ? -1.0 : 1.0;
  rows[0] = l - mm; vx[0] = 0.0; vy[0] = -sg * r2;
  rows[1] = l + mm; vx[1] = 0.0; vy[1] = sg * par * r2;
  return 2;
}

constexpr int KCL [11] = {0,0,0, 2,2,2,2, 4,4,4,4};
constexpr int KCL1[11] = {0,2,4, 0,2,2,4, 0,2,2,4};
constexpr int KCL2[11] = {0,2,4, 2,2,4,4, 4,2,4,4};
constexpr int KOFF[11] = {0,1,26,107,132,257,482,887,968,1193,1598};

struct CCGT { double v[11][81]; };
constexpr CCGT make_ccg() {
  CCGT z = {};
  for (int c = 0; c < 11; ++c) {
    int l = KCL[c], l1 = KCL1[c], l2 = KCL2[c];
    int D1 = 2 * l1 + 1, D2 = 2 * l2 + 1;
    for (int a = 0; a < D1; ++a)
      for (int b = 0; b < D2; ++b) {
        int m1 = a - l1, m2 = b - l2, m3 = m1 + m2;
        z.v[c][a * D2 + b] =
            (m3 >= -l && m3 <= l) ? su2cg_c(l1, m1, l2, m2, l, m3) : 0.0;
      }
  }
  return z;
}
constexpr CCGT CCG = make_ccg();

struct CGTab { float r[2327]; float l[2327]; };
constexpr CGTab make_tables(const CCGT& cc) {
  CGTab t = {};
  for (int c = 0; c < 11; ++c) {
    int l = KCL[c], l1 = KCL1[c], l2 = KCL2[c];
    int D = 2 * l + 1, D1 = 2 * l1 + 1, D2 = 2 * l2 + 1;
    int n = D * D1 * D2, off = KOFF[c];
    double wbuf[729] = {};
    for (int e = 0; e < n; ++e) {
      int k = e % D; int ab = e / D; int b = ab % D2; int a = ab / D2;
      int r1[2] = {}, r2[2] = {}, r3[2] = {};
      double x1[2] = {}, y1[2] = {}, x2[2] = {}, y2[2] = {}, x3[2] = {}, y3[2] = {};
      int n1 = nqcol(l1, a, r1, x1, y1);
      int n2 = nqcol(l2, b, r2, x2, y2);
      int n3 = nqcol(l, k, r3, x3, y3);
      double s = 0.0;
      for (int i1 = 0; i1 < n1; ++i1)
        for (int i2 = 0; i2 < n2; ++i2) {
          double px = x1[i1] * x2[i2] - y1[i1] * y2[i2];
          double py = x1[i1] * y2[i2] + y1[i1] * x2[i2];
          int m12 = (r1[i1] - l1) + (r2[i2] - l2);
          for (int i3 = 0; i3 < n3; ++i3) {
            if (r3[i3] - l != m12) continue;
            s += (px * x3[i3] + py * y3[i3]) * cc.v[c][r1[i1] * D2 + r2[i2]];
          }
        }
      wbuf[e] = s;
    }
    double ss = 0.0;
    for (int e = 0; e < n; ++e) ss += wbuf[e] * wbuf[e];
    double inv = (l1 != l2 ? 1.41421356237309504880 : 1.0) / csqrt(ss);
    for (int o = 0; o < n; ++o) {
      int k = o / (D1 * D2), tt = o % (D1 * D2);
      int a = tt % D1, b = tt / D1;   // w[a][b][k]
      int x = tt / D2, y = tt % D2;   // cg_r[k][x][y]  (x,y unused in index math)
      double val = wbuf[(a * D2 + b) * D + k] * inv;
      t.r[off + o] = (float)val;                          // k*D1*D2 + x*D2 + y
      t.l[off + k * (D1 * D2) + y * D1 + x] = (float)val; // k*D1*D2 + y*D1 + x
    }
  }
  return t;
}
__constant__ CGTab G = make_tables(CCG);

// setup: block 0 copies CG tables G -> ws (opaque pointer for quad_main);
// block 1 writes the feats passthrough. ~2 us.
__global__ void setup_copy(float* __restrict__ ws,
                           const float* __restrict__ feats,
                           float* __restrict__ out) {
  int tid = threadIdx.x;
  if (blockIdx.x == 0) {
    for (int i = tid; i < 2327; i += 256) {
      ws[i] = G.r[i];
      ws[2327 + i] = G.l[i];
    }
  } else {
    for (int i = tid; i < 1024; i += 256) {
      int n = i >> 6, j = i & 63;
      out[7012352 + n * 12352 + j] = feats[i];
    }
  }
}

// ================= main compute (exact R1 structure, measured 140 us) =====
// LDS layout: lds[elem*65 + site], elem: 0 = rh0, 1..25 = rh2, 26..106 = rh4

template<int D, int D1, int D2>
DEV void run_combo(const float* __restrict__ cgr, const float* __restrict__ cgl,
                   const float* __restrict__ A, const float* __restrict__ B,
                   int lane, float* __restrict__ acc, int q0, int q1) {
  #pragma unroll 1
  for (int q = q0; q < q1; ++q) {
    float Brow[D2];
    #pragma unroll
    for (int j = 0; j < D2; ++j) Brow[j] = B[(q * D2 + j) * 65 + lane];
    const float* cglq = cgl + q * D1;
    #pragma unroll 1
    for (int p = 0; p < D1; ++p) {
      float Acol[D1];
      #pragma unroll
      for (int j = 0; j < D1; ++j) Acol[j] = A[(j * D1 + p) * 65 + lane];
      const float* cgrp = cgr + p * D2;
      float vl[D], vr[D];
      #pragma unroll
      for (int k = 0; k < D; ++k) {
        float s = 0.f;
        #pragma unroll
        for (int j = 0; j < D1; ++j) s = fmaf(Acol[j], cglq[k * D1 * D2 + j], s);
        vl[k] = s;
      }
      #pragma unroll
      for (int k = 0; k < D; ++k) {
        float s = 0.f;
        #pragma unroll
        for (int j = 0; j < D2; ++j) s = fmaf(Brow[j], cgrp[k * D1 * D2 + j], s);
        vr[k] = s;
      }
      #pragma unroll
      for (int k1 = 0; k1 < D; ++k1) {
        #pragma unroll
        for (int k2 = 0; k2 < D; ++k2)
          acc[k1 * D + k2] = fmaf(vl[k1], vr[k2], acc[k1 * D + k2]);
      }
    }
  }
}

// bounds(256,2): measured-good. (256,4) spilled (R2); (256,3) regressed
// codegen 140->230 us with occupancy unchanged (R3). Do not touch.
__global__ __launch_bounds__(256, 2)
void quad_main(const float* __restrict__ rh0, const float* __restrict__ rh2,
               const float* __restrict__ rh4, const float* __restrict__ ws,
               float* __restrict__ out) {
  __shared__ float lds[107 * 65];
  const int tid = threadIdx.x;
  const int lane = tid & 63;
  const int wave = tid >> 6;
  const int blk = blockIdx.x;
  const int site0 = blk * 64;

  // stage 64 sites into LDS (coalesced global reads, conflict-free LDS writes)
  if (tid < 64) lds[tid] = rh0[site0 + tid];
  for (int f = tid; f < 1600; f += 256) {
    int s = f / 25, e = f - s * 25;
    lds[(1 + e) * 65 + s] = rh2[site0 * 25 + f];
  }
  for (int f = tid; f < 5184; f += 256) {
    int s = f / 81, e = f - s * 81;
    lds[(26 + e) * 65 + s] = rh4[site0 * 81 + f];
  }
  __syncthreads();

  const float* r0 = lds;
  const float* r2l = lds + 65;
  const float* r4l = lds + 26 * 65;
  const float* CGR = ws;
  const float* CGL = ws + 2327;

  float acc0[1] = {0.f};
  float acc2[25], acc4[81];
  #pragma unroll
  for (int i = 0; i < 25; ++i) acc2[i] = 0.f;
  #pragma unroll
  for (int i = 0; i < 81; ++i) acc4[i] = 0.f;

  // combo work split across the 4 waves (R1 split, max 13590 FMA/wave)
  if (wave == 0) {
    run_combo<9,9,9>(CGR + 1598, CGL + 1598, r4l, r4l, lane, acc4, 0, 5);  // c10 q0-4
  } else if (wave == 1) {
    run_combo<5,9,9>(CGR + 482, CGL + 482, r4l, r4l, lane, acc2, 0, 9);    // (2,4,4)
    run_combo<5,5,9>(CGR + 257, CGL + 257, r2l, r4l, lane, acc2, 0, 9);    // (2,2,4)
  } else if (wave == 2) {
    run_combo<9,5,9>(CGR + 1193, CGL + 1193, r2l, r4l, lane, acc4, 0, 9);  // (4,2,4)
    run_combo<9,5,5>(CGR + 968, CGL + 968, r2l, r2l, lane, acc4, 0, 5);    // (4,2,2)
  } else {
    run_combo<9,9,9>(CGR + 1598, CGL + 1598, r4l, r4l, lane, acc4, 5, 9);  // c10 q5-8
    run_combo<1,9,9>(CGR + 26, CGL + 26, r4l, r4l, lane, acc0, 0, 9);      // (0,4,4)
    run_combo<9,1,9>(CGR + 887, CGL + 887, r0, r4l, lane, acc4, 0, 9);     // (4,0,4)
    run_combo<5,5,5>(CGR + 132, CGL + 132, r2l, r2l, lane, acc2, 0, 5);    // (2,2,2)
    run_combo<5,1,5>(CGR + 107, CGL + 107, r0, r2l, lane, acc2, 0, 5);     // (2,0,2)
    run_combo<1,5,5>(CGR + 1, CGL + 1, r2l, r2l, lane, acc0, 0, 5);        // (0,2,2)
    run_combo<1,1,1>(CGR + 0, CGL + 0, r0, r0, lane, acc0, 0, 1);          // (0,0,0)
  }

  // merge partial accumulators through LDS (staging data is dead now)
  __syncthreads();
  if (wave == 0) {
    lds[lane] = acc0[0];
    #pragma unroll
    for (int e = 0; e < 25; ++e) lds[(1 + e) * 65 + lane] = acc2[e];
    #pragma unroll
    for (int e = 0; e < 81; ++e) lds[(26 + e) * 65 + lane] = acc4[e];
  }
  __syncthreads();
  if (wave == 1) {
    lds[lane] += acc0[0];
    #pragma unroll
    for (int e = 0; e < 25; ++e) lds[(1 + e) * 65 + lane] += acc2[e];
    #pragma unroll
    for (int e = 0; e < 81; ++e) lds[(26 + e) * 65 + lane] += acc4[e];
  }
  __syncthreads();
  if (wave == 2) {
    lds[lane] += acc0[0];
    #pragma unroll
    for (int e = 0; e < 25; ++e) lds[(1 + e) * 65 + lane] += acc2[e];
    #pragma unroll
    for (int e = 0; e < 81; ++e) lds[(26 + e) * 65 + lane] += acc4[e];
  }
  __syncthreads();
  if (wave == 3) {
    lds[lane] += acc0[0];
    #pragma unroll
    for (int e = 0; e < 25; ++e) lds[(1 + e) * 65 + lane] += acc2[e];
    #pragma unroll
    for (int e = 0; e < 81; ++e) lds[(26 + e) * 65 + lane] += acc4[e];
  }
  __syncthreads();

  // coalesced stores: rh_n[0] | rh_n[2] | rh_n[4]
  if (tid < 64) out[site0 + tid] = lds[tid];
  for (int f = tid; f < 1600; f += 256) {
    int s = f / 25, e = f - s * 25;
    out[65536 + blk * 1600 + f] = lds[(1 + e) * 65 + s];
  }
  for (int f = tid; f < 5184; f += 256) {
    int s = f / 81, e = f - s * 81;
    out[1703936 + blk * 5184 + f] = lds[(26 + e) * 65 + s];
  }

  // rotation-invariant features
  if (tid < 64) {
    int site = site0 + tid;
    int nn = site >> 12, abc = site & 4095;
    float v0 = lds[tid];
    float f0 = v0 * v0;
    float s2 = 0.f;
    #pragma unroll
    for (int e = 0; e < 25; ++e) { float v = lds[(1 + e) * 65 + tid]; s2 = fmaf(v, v, s2); }
    float s4 = 0.f;
    #pragma unroll
    for (int e = 0; e < 81; ++e) { float v = lds[(26 + e) * 65 + tid]; s4 = fmaf(v, v, s4); }
    const float PI8 = 78.95683520871486f;  // 8*pi^2
    int base = 7012352 + nn * 12352 + 64;
    out[base + abc] = PI8 * f0;
    out[base + 4096 + abc] = (PI8 / 5.f) * s2;
    out[base + 8192 + abc] = (PI8 / 9.f) * s4;
  }
}

extern "C" void kernel_launch(void* const* d_in, const int* in_sizes, int n_in,
                              void* d_out, int out_size, void* d_ws, size_t ws_size,
                              hipStream_t stream) {
  const float* rh0 = (const float*)d_in[0];
  const float* rh2 = (const float*)d_in[1];
  const float* rh4 = (const float*)d_in[2];
  const float* feats = (const float*)d_in[3];
  float* out = (float*)d_out;
  float* ws = (float*)d_ws;
  setup_copy<<<2, 256, 0, stream>>>(ws, feats, out);
  quad_main<<<1024, 256, 0, stream>>>(rh0, rh2, rh4, ws, out);
}

// Round 5
// 171.709 us; speedup vs baseline: 3.9429x; 1.1944x over previous
//
#include <hip/hip_runtime.h>
#include <math.h>
#include <utility>

#define DEV __device__ __forceinline__

// ================= compile-time CG tables =================
// All Wigner/CG math at compile time. cg_r is consumed as constexpr
// immediates inside templated combo bodies (sparsity folded, ~75% of vr
// FMAs eliminated); cg_l is copied to ws and read through an OPAQUE
// runtime pointer (R3 showed full const-folding of BOTH sides regresses
// codegen badly; this hybrid keeps code size ~24KB < 32KB I-cache).

constexpr double FC[14] = {1.,1.,2.,6.,24.,120.,720.,5040.,40320.,362880.,
                           3628800.,39916800.,479001600.,6227020800.};

constexpr double csqrt(double x) {
  if (x <= 0.0) return 0.0;
  double g = x > 1.0 ? x : 1.0;
  double p = 0.0;
  for (int i = 0; i < 64 && g != p; ++i) { p = g; g = 0.5 * (g + x / g); }
  return g;
}

constexpr int cimax(int a, int b) { return a > b ? a : b; }
constexpr int cimin(int a, int b) { return a < b ? a : b; }

constexpr double su2cg_c(int j1, int m1, int j2, int m2, int j3, int m3) {
  if (m3 != m1 + m2) return 0.0;
  int vmin = cimax(cimax(-j1 + j2 + m3, -j1 + m1), 0);
  int vmax = cimin(cimin(j2 + j3 + m1, j3 - j1 + j2), j3 + m3);
  if (vmax < vmin) return 0.0;
  double C = csqrt((2.0 * j3 + 1.0)
      * FC[j3 + j1 - j2] * FC[j3 - j1 + j2] * FC[j1 + j2 - j3]
      * FC[j3 + m3] * FC[j3 - m3]
      / (FC[j1 + j2 + j3 + 1] * FC[j1 - m1] * FC[j1 + m1]
         * FC[j2 - m2] * FC[j2 + m2]));
  double S = 0.0;
  for (int v = vmin; v <= vmax; ++v) {
    double term = FC[j2 + j3 + m1 - v] * FC[j1 - m1 + v]
        / (FC[v] * FC[j3 - j1 + j2 - v] * FC[j3 + m3 - v]
           * FC[v + j1 - j2 - m3]);
    S += ((v + j2 + m2) & 1) ? -term : term;
  }
  return C * S;
}

constexpr int nqcol(int l, int c, int* rows, double* vx, double* vy) {
  const double r2 = 0.70710678118654752440;
  double sg = (l % 4 == 2) ? -1.0 : 1.0;
  if (c == l) { rows[0] = l; vx[0] = sg; vy[0] = 0.0; return 1; }
  if (c > l) {
    int mm = c - l;
    double par = (mm & 1) ? -1.0 : 1.0;
    rows[0] = l - mm; vx[0] = sg * r2;       vy[0] = 0.0;
    rows[1] = l + mm; vx[1] = sg * par * r2; vy[1] = 0.0;
    return 2;
  }
  int mm = l - c;
  double par = (mm & 1) ? -1.0 : 1.0;
  rows[0] = l - mm; vx[0] = 0.0; vy[0] = -sg * r2;
  rows[1] = l + mm; vx[1] = 0.0; vy[1] = sg * par * r2;
  return 2;
}

constexpr int KCL [11] = {0,0,0, 2,2,2,2, 4,4,4,4};
constexpr int KCL1[11] = {0,2,4, 0,2,2,4, 0,2,2,4};
constexpr int KCL2[11] = {0,2,4, 2,2,4,4, 4,2,4,4};
constexpr int KOFF[11] = {0,1,26,107,132,257,482,887,968,1193,1598};

struct CCGT { double v[11][81]; };
constexpr CCGT make_ccg() {
  CCGT z = {};
  for (int c = 0; c < 11; ++c) {
    int l = KCL[c], l1 = KCL1[c], l2 = KCL2[c];
    int D1 = 2 * l1 + 1, D2 = 2 * l2 + 1;
    for (int a = 0; a < D1; ++a)
      for (int b = 0; b < D2; ++b) {
        int m1 = a - l1, m2 = b - l2, m3 = m1 + m2;
        z.v[c][a * D2 + b] =
            (m3 >= -l && m3 <= l) ? su2cg_c(l1, m1, l2, m2, l, m3) : 0.0;
      }
  }
  return z;
}
constexpr CCGT CCG = make_ccg();

struct CGTab { float r[2327]; float l[2327]; };
constexpr CGTab make_tables(const CCGT& cc) {
  CGTab t = {};
  for (int c = 0; c < 11; ++c) {
    int l = KCL[c], l1 = KCL1[c], l2 = KCL2[c];
    int D = 2 * l + 1, D1 = 2 * l1 + 1, D2 = 2 * l2 + 1;
    int n = D * D1 * D2, off = KOFF[c];
    double wbuf[729] = {};
    for (int e = 0; e < n; ++e) {
      int k = e % D; int ab = e / D; int b = ab % D2; int a = ab / D2;
      int r1[2] = {}, r2[2] = {}, r3[2] = {};
      double x1[2] = {}, y1[2] = {}, x2[2] = {}, y2[2] = {}, x3[2] = {}, y3[2] = {};
      int n1 = nqcol(l1, a, r1, x1, y1);
      int n2 = nqcol(l2, b, r2, x2, y2);
      int n3 = nqcol(l, k, r3, x3, y3);
      double s = 0.0;
      for (int i1 = 0; i1 < n1; ++i1)
        for (int i2 = 0; i2 < n2; ++i2) {
          double px = x1[i1] * x2[i2] - y1[i1] * y2[i2];
          double py = x1[i1] * y2[i2] + y1[i1] * x2[i2];
          int m12 = (r1[i1] - l1) + (r2[i2] - l2);
          for (int i3 = 0; i3 < n3; ++i3) {
            if (r3[i3] - l != m12) continue;
            s += (px * x3[i3] + py * y3[i3]) * cc.v[c][r1[i1] * D2 + r2[i2]];
          }
        }
      wbuf[e] = s;
    }
    double ss = 0.0;
    for (int e = 0; e < n; ++e) ss += wbuf[e] * wbuf[e];
    double inv = (l1 != l2 ? 1.41421356237309504880 : 1.0) / csqrt(ss);
    for (int o = 0; o < n; ++o) {
      int k = o / (D1 * D2), tt = o % (D1 * D2);
      int a = tt % D1, b = tt / D1;   // w[a][b][k]
      int x = tt / D2, y = tt % D2;
      double val = wbuf[(a * D2 + b) * D + k] * inv;
      t.r[off + o] = (float)val;                          // k*D1*D2 + x*D2 + y
      t.l[off + k * (D1 * D2) + y * D1 + x] = (float)val; // k*D1*D2 + y*D1 + x
    }
  }
  return t;
}
constexpr CGTab GT = make_tables(CCG);
__constant__ CGTab G = GT;

// setup: block 0 copies cg_l -> ws (opaque pointer for quad_main's vl side);
// block 1 writes the feats passthrough. ~2 us.
__global__ void setup_copy(float* __restrict__ ws,
                           const float* __restrict__ feats,
                           float* __restrict__ out) {
  int tid = threadIdx.x;
  if (blockIdx.x == 0) {
    for (int i = tid; i < 2327; i += 256) ws[i] = G.l[i];
  } else {
    for (int i = tid; i < 1024; i += 256) {
      int n = i >> 6, j = i & 63;
      out[7012352 + n * 12352 + j] = feats[i];
    }
  }
}

// ================= sparse combo machinery =================
// vr[k] = sum_i Brow[i] * cg_r[k][P][i], CG constexpr, zeros folded out.

template<int OFF, int D1, int D2, int P, int K>
constexpr bool vr_row_nz() {
  for (int i = 0; i < D2; ++i)
    if (GT.r[OFF + K * D1 * D2 + P * D2 + i] != 0.0f) return true;
  return false;
}

template<int OFF, int D1, int D2, int P, int K, int I>
DEV void vr_step(const float* __restrict__ Brow, float& s) {
  constexpr float c = GT.r[OFF + K * D1 * D2 + P * D2 + I];
  if constexpr (c != 0.0f) s = fmaf(Brow[I], c, s);
}

template<int OFF, int D1, int D2, int P, int K, int... Is>
DEV float vr_k(const float* __restrict__ Brow, std::integer_sequence<int, Is...>) {
  float s = 0.f;
  (vr_step<OFF, D1, D2, P, K, Is>(Brow, s), ...);
  return s;
}

template<int OFF, int D, int D1, int D2, int P, int... Ks>
DEV void vr_all(const float* __restrict__ Brow, float* __restrict__ vr,
                std::integer_sequence<int, Ks...>) {
  ((vr[Ks] = vr_k<OFF, D1, D2, P, Ks>(Brow, std::make_integer_sequence<int, D2>{})), ...);
}

template<int OFF, int D, int D1, int D2, int P, int K1, int K2>
DEV void acc_one(const float* __restrict__ vl, const float* __restrict__ vr,
                 float* __restrict__ acc) {
  if constexpr (vr_row_nz<OFF, D1, D2, P, K2>())
    acc[K1 * D + K2] = fmaf(vl[K1], vr[K2], acc[K1 * D + K2]);
}

template<int OFF, int D, int D1, int D2, int P, int K1, int... K2s>
DEV void acc_row(const float* __restrict__ vl, const float* __restrict__ vr,
                 float* __restrict__ acc, std::integer_sequence<int, K2s...>) {
  (acc_one<OFF, D, D1, D2, P, K1, K2s>(vl, vr, acc), ...);
}

template<int OFF, int D, int D1, int D2, int P, int... K1s>
DEV void acc_all(const float* __restrict__ vl, const float* __restrict__ vr,
                 float* __restrict__ acc, std::integer_sequence<int, K1s...>) {
  (acc_row<OFF, D, D1, D2, P, K1s>(vl, vr, acc, std::make_integer_sequence<int, D>{}), ...);
}

// one body = one compile-time p; q rolled at runtime.
// vl (dense, CG from opaque ws) issues while Brow ds_reads are in flight.
template<int C, int D, int D1, int D2, int P>
DEV void body(const float* __restrict__ cglws, const float* __restrict__ A,
              const float* __restrict__ B, int lane, float* __restrict__ acc) {
  constexpr int OFF = KOFF[C];
  float Acol[D1];
  #pragma unroll
  for (int j = 0; j < D1; ++j) Acol[j] = A[(j * D1 + P) * 65 + lane];
  #pragma unroll 1
  for (int q = 0; q < D2; ++q) {
    float Brow[D2];
    #pragma unroll
    for (int i = 0; i < D2; ++i) Brow[i] = B[(q * D2 + i) * 65 + lane];
    float vl[D];
    #pragma unroll
    for (int k = 0; k < D; ++k) {
      float s = 0.f;
      #pragma unroll
      for (int j = 0; j < D1; ++j)
        s = fmaf(Acol[j], cglws[k * D1 * D2 + q * D1 + j], s);
      vl[k] = s;
    }
    float vr[D];
    vr_all<OFF, D, D1, D2, P>(Brow, vr, std::make_integer_sequence<int, D>{});
    acc_all<OFF, D, D1, D2, P>(vl, vr, acc, std::make_integer_sequence<int, D>{});
  }
}

template<int C, int D, int D1, int D2, int P0, int... Ps>
DEV void combo_impl(const float* __restrict__ cglws, const float* __restrict__ A,
                    const float* __restrict__ B, int lane, float* __restrict__ acc,
                    std::integer_sequence<int, Ps...>) {
  (body<C, D, D1, D2, P0 + Ps>(cglws, A, B, lane, acc), ...);
}

// combo C over p in [P0,P1)
template<int C, int D, int D1, int D2, int P0, int P1>
DEV void combo(const float* __restrict__ ws, const float* __restrict__ A,
               const float* __restrict__ B, int lane, float* __restrict__ acc) {
  combo_impl<C, D, D1, D2, P0>(ws + KOFF[C], A, B, lane, acc,
                               std::make_integer_sequence<int, P1 - P0>{});
}

// ================= main compute =================
// LDS layout: lds[elem*65 + site], elem: 0 = rh0, 1..25 = rh2, 26..106 = rh4
// bounds(256,2): measured-good. (256,4) spilled (R2); (256,3) regressed
// codegen 140->230 us (R3). Do not touch.
__global__ __launch_bounds__(256, 2)
void quad_main(const float* __restrict__ rh0, const float* __restrict__ rh2,
               const float* __restrict__ rh4, const float* __restrict__ ws,
               float* __restrict__ out) {
  __shared__ float lds[107 * 65];
  const int tid = threadIdx.x;
  const int lane = tid & 63;
  const int wave = tid >> 6;
  const int blk = blockIdx.x;
  const int site0 = blk * 64;

  // stage 64 sites into LDS (coalesced global reads, conflict-free LDS writes)
  if (tid < 64) lds[tid] = rh0[site0 + tid];
  for (int f = tid; f < 1600; f += 256) {
    int s = f / 25, e = f - s * 25;
    lds[(1 + e) * 65 + s] = rh2[site0 * 25 + f];
  }
  for (int f = tid; f < 5184; f += 256) {
    int s = f / 81, e = f - s * 81;
    lds[(26 + e) * 65 + s] = rh4[site0 * 81 + f];
  }
  __syncthreads();

  const float* r0 = lds;
  const float* r2l = lds + 65;
  const float* r4l = lds + 26 * 65;

  float acc0[1] = {0.f};
  float acc2[25], acc4[81];
  #pragma unroll
  for (int i = 0; i < 25; ++i) acc2[i] = 0.f;
  #pragma unroll
  for (int i = 0; i < 81; ++i) acc4[i] = 0.f;

  // p-split across waves; sparse FMA/wave ~ 9720 / 9180 / 9200 / 9250
  if (wave == 0) {
    combo<10,9,9,9,0,6>(ws, r4l, r4l, lane, acc4);   // (4,4,4) p0-5
  } else if (wave == 1) {
    combo<6,5,9,9,0,9>(ws, r4l, r4l, lane, acc2);    // (2,4,4)
    combo<5,5,5,9,0,5>(ws, r2l, r4l, lane, acc2);    // (2,2,4)
  } else if (wave == 2) {
    combo<9,9,5,9,0,5>(ws, r2l, r4l, lane, acc4);    // (4,2,4)
    combo<8,9,5,5,0,4>(ws, r2l, r2l, lane, acc4);    // (4,2,2) p0-3
  } else {
    combo<10,9,9,9,6,9>(ws, r4l, r4l, lane, acc4);   // (4,4,4) p6-8
    combo<8,9,5,5,4,5>(ws, r2l, r2l, lane, acc4);    // (4,2,2) p4
    combo<7,9,1,9,0,1>(ws, r0, r4l, lane, acc4);     // (4,0,4)
    combo<4,5,5,5,0,5>(ws, r2l, r2l, lane, acc2);    // (2,2,2)
    combo<3,5,1,5,0,1>(ws, r0, r2l, lane, acc2);     // (2,0,2)
    combo<2,1,9,9,0,9>(ws, r4l, r4l, lane, acc0);    // (0,4,4)
    combo<1,1,5,5,0,5>(ws, r2l, r2l, lane, acc0);    // (0,2,2)
    combo<0,1,1,1,0,1>(ws, r0, r0, lane, acc0);      // (0,0,0)
  }

  // merge partial accumulators through LDS (staging data is dead now)
  __syncthreads();
  if (wave == 0) {
    lds[lane] = acc0[0];
    #pragma unroll
    for (int e = 0; e < 25; ++e) lds[(1 + e) * 65 + lane] = acc2[e];
    #pragma unroll
    for (int e = 0; e < 81; ++e) lds[(26 + e) * 65 + lane] = acc4[e];
  }
  __syncthreads();
  if (wave == 1) {
    lds[lane] += acc0[0];
    #pragma unroll
    for (int e = 0; e < 25; ++e) lds[(1 + e) * 65 + lane] += acc2[e];
    #pragma unroll
    for (int e = 0; e < 81; ++e) lds[(26 + e) * 65 + lane] += acc4[e];
  }
  __syncthreads();
  if (wave == 2) {
    lds[lane] += acc0[0];
    #pragma unroll
    for (int e = 0; e < 25; ++e) lds[(1 + e) * 65 + lane] += acc2[e];
    #pragma unroll
    for (int e = 0; e < 81; ++e) lds[(26 + e) * 65 + lane] += acc4[e];
  }
  __syncthreads();
  if (wave == 3) {
    lds[lane] += acc0[0];
    #pragma unroll
    for (int e = 0; e < 25; ++e) lds[(1 + e) * 65 + lane] += acc2[e];
    #pragma unroll
    for (int e = 0; e < 81; ++e) lds[(26 + e) * 65 + lane] += acc4[e];
  }
  __syncthreads();

  // coalesced stores: rh_n[0] | rh_n[2] | rh_n[4]
  if (tid < 64) out[site0 + tid] = lds[tid];
  for (int f = tid; f < 1600; f += 256) {
    int s = f / 25, e = f - s * 25;
    out[65536 + blk * 1600 + f] = lds[(1 + e) * 65 + s];
  }
  for (int f = tid; f < 5184; f += 256) {
    int s = f / 81, e = f - s * 81;
    out[1703936 + blk * 5184 + f] = lds[(26 + e) * 65 + s];
  }

  // rotation-invariant features
  if (tid < 64) {
    int site = site0 + tid;
    int nn = site >> 12, abc = site & 4095;
    float v0 = lds[tid];
    float f0 = v0 * v0;
    float s2 = 0.f;
    #pragma unroll
    for (int e = 0; e < 25; ++e) { float v = lds[(1 + e) * 65 + tid]; s2 = fmaf(v, v, s2); }
    float s4 = 0.f;
    #pragma unroll
    for (int e = 0; e < 81; ++e) { float v = lds[(26 + e) * 65 + tid]; s4 = fmaf(v, v, s4); }
    const float PI8 = 78.95683520871486f;  // 8*pi^2
    int base = 7012352 + nn * 12352 + 64;
    out[base + abc] = PI8 * f0;
    out[base + 4096 + abc] = (PI8 / 5.f) * s2;
    out[base + 8192 + abc] = (PI8 / 9.f) * s4;
  }
}

extern "C" void kernel_launch(void* const* d_in, const int* in_sizes, int n_in,
                              void* d_out, int out_size, void* d_ws, size_t ws_size,
                              hipStream_t stream) {
  const float* rh0 = (const float*)d_in[0];
  const float* rh2 = (const float*)d_in[1];
  const float* rh4 = (const float*)d_in[2];
  const float* feats = (const float*)d_in[3];
  float* out = (float*)d_out;
  float* ws = (float*)d_ws;
  setup_copy<<<2, 256, 0, stream>>>(ws, feats, out);
  quad_main<<<1024, 256, 0, stream>>>(rh0, rh2, rh4, ws, out);
}